// Round 5
// 272.350 us; speedup vs baseline: 1.0173x; 1.0173x over previous
//
#include <hip/hip_runtime.h>
#include <hip/hip_bf16.h>

#define EMBED 1024
#define NH 16
#define HD 64
#define BSZ 4
#define SSZ 2048
#define LSTR 72   // LDS row stride (shorts) for qkv kernel; 144 B rows => 16B-aligned

typedef __attribute__((ext_vector_type(8))) short short8;
typedef __attribute__((ext_vector_type(4))) short short4v;
typedef __attribute__((ext_vector_type(4))) float float4v;
typedef __attribute__((ext_vector_type(16))) float float16v;
typedef __attribute__((ext_vector_type(2))) unsigned int uint2v;
typedef __attribute__((ext_vector_type(4))) unsigned int uint4v;

__device__ inline float4v mfma16(short8 a, short8 b, float4v c) {
    return __builtin_amdgcn_mfma_f32_16x16x32_bf16(a, b, c, 0, 0, 0);
}
__device__ inline float16v mfma32(short8 a, short8 b, float16v c) {
    return __builtin_amdgcn_mfma_f32_32x32x16_bf16(a, b, c, 0, 0, 0);
}

__device__ inline float fexp2(float x) { return __builtin_amdgcn_exp2f(x); }

__device__ inline short f2bf(float f) {
    unsigned u = __builtin_bit_cast(unsigned, f);
    return (short)((u + 0x8000u) >> 16);
}
__device__ inline unsigned pk2(float a, float b) {
    unsigned ua = __builtin_bit_cast(unsigned, a);
    unsigned ub = __builtin_bit_cast(unsigned, b);
    return ((ua + 0x8000u) >> 16) | (((ub + 0x8000u) >> 16) << 16);
}
// packed f32x2 -> bf16x2 (RNE), single instruction
__device__ inline unsigned cvtpk(float a, float b) {
    unsigned r;
    asm("v_cvt_pk_bf16_f32 %0, %1, %2" : "=v"(r) : "v"(a), "v"(b));
    return r;
}
__device__ inline short8 ld8_f32_bf16(const float* p) {
    float4v lo = *(const float4v*)p;
    float4v hi = *(const float4v*)(p + 4);
    short8 r;
#pragma unroll
    for (int i = 0; i < 4; ++i) { r[i] = f2bf(lo[i]); r[i + 4] = f2bf(hi[i]); }
    return r;
}

// async global->LDS, 16B per lane; ldst must be wave-uniform base
__device__ inline void glds16(const short* gsrc, short* ldst) {
    __builtin_amdgcn_global_load_lds(
        (const __attribute__((address_space(1))) unsigned int*)gsrc,
        (__attribute__((address_space(3))) unsigned int*)ldst,
        16, 0, 0);
}

// ---------------- Kernel 0: convert W_p (fp32) -> bf16 ----------------
__global__ __launch_bounds__(256) void wp_cvt_kernel(
    const float* __restrict__ Wp, short* __restrict__ Wpb)
{
    int i = (blockIdx.x * 256 + threadIdx.x) * 4;
    float4v v = *(const float4v*)(Wp + i);
    short4v s;
#pragma unroll
    for (int j = 0; j < 4; ++j) s[j] = f2bf(v[j]);
    *(short4v*)(Wpb + i) = s;
}

// ---------------- Kernel 1: per-head QKV projection (LDS-staged) ----------
__global__ __launch_bounds__(256) void qkv_kernel(
    const float* __restrict__ q_in, const float* __restrict__ k_in,
    const float* __restrict__ v_in,
    const float* __restrict__ Wq, const float* __restrict__ bq,
    const float* __restrict__ Wk, const float* __restrict__ bk,
    const float* __restrict__ Wv, const float* __restrict__ bv,
    short* __restrict__ qp, short* __restrict__ kp, short* __restrict__ vt)
{
    __shared__ __align__(16) short Xb[64 * LSTR];
    __shared__ __align__(16) short Wb[64 * LSTR];

    int z = blockIdx.z;
    const float* X    = z == 0 ? q_in : (z == 1 ? k_in : v_in);
    const float* W    = z == 0 ? Wq   : (z == 1 ? Wk   : Wv);
    const float* bias = z == 0 ? bq   : (z == 1 ? bk   : bv);
    const float scale = z == 0 ? 0.125f * 1.44269504f : 1.0f;

    int tid = threadIdx.x;
    int wave = tid >> 6, lane = tid & 63, quad = lane >> 4, l16 = lane & 15;
    int h = blockIdx.y;
    int rbase = blockIdx.x * 64;
    int b = rbase >> 11;
    int sbase = rbase & (SSZ - 1);
    int bh = b * NH + h;

    int srow = tid >> 2, c16 = (tid & 3) * 16;
    {
        const float* xsrc = X + (size_t)(rbase + srow) * EMBED + h * HD + c16;
        short8 x0 = ld8_f32_bf16(xsrc);
        short8 x1 = ld8_f32_bf16(xsrc + 8);
        *(short8*)&Xb[srow * LSTR + c16] = x0;
        *(short8*)&Xb[srow * LSTR + c16 + 8] = x1;
        const float* wsrc = W + (size_t)srow * HD + c16;
        short8 w0 = ld8_f32_bf16(wsrc);
        short8 w1 = ld8_f32_bf16(wsrc + 8);
        *(short8*)&Wb[srow * LSTR + c16] = w0;
        *(short8*)&Wb[srow * LSTR + c16 + 8] = w1;
    }
    __syncthreads();

    short8 a0 = *(const short8*)&Xb[(wave * 16 + l16) * LSTR + quad * 8];
    short8 a1 = *(const short8*)&Xb[(wave * 16 + l16) * LSTR + 32 + quad * 8];
    float4v acc[4];
#pragma unroll
    for (int nt = 0; nt < 4; ++nt) acc[nt] = (float4v)(0.f);
#pragma unroll
    for (int nt = 0; nt < 4; ++nt) {
        short8 b0 = *(const short8*)&Wb[(nt * 16 + l16) * LSTR + quad * 8];
        short8 b1 = *(const short8*)&Wb[(nt * 16 + l16) * LSTR + 32 + quad * 8];
        acc[nt] = mfma16(a0, b0, acc[nt]);
        acc[nt] = mfma16(a1, b1, acc[nt]);
    }
    __syncthreads();

    if (z < 2) {
#pragma unroll
        for (int nt = 0; nt < 4; ++nt) {
            float bv_ = bias[nt * 16 + l16];
#pragma unroll
            for (int r = 0; r < 4; ++r) {
                float val = (acc[nt][r] + bv_) * scale;
                Xb[(wave * 16 + quad * 4 + r) * LSTR + nt * 16 + l16] = f2bf(val);
            }
        }
        __syncthreads();
        short8 r0 = *(const short8*)&Xb[srow * LSTR + c16];
        short8 r1 = *(const short8*)&Xb[srow * LSTR + c16 + 8];
        short* Y = z == 0 ? qp : kp;
        size_t o = ((size_t)bh * SSZ + sbase + srow) * HD + c16;
        *(short8*)&Y[o] = r0;
        *(short8*)&Y[o + 8] = r1;
    } else {
#pragma unroll
        for (int nt = 0; nt < 4; ++nt) {
            float bv_ = bias[nt * 16 + l16];
            uint2v p;
            p[0] = pk2(acc[nt][0] + bv_, acc[nt][1] + bv_);
            p[1] = pk2(acc[nt][2] + bv_, acc[nt][3] + bv_);
            *(uint2v*)&Xb[(nt * 16 + l16) * LSTR + wave * 16 + quad * 4] = p;
        }
        __syncthreads();
        short8 r0 = *(const short8*)&Xb[srow * LSTR + c16];
        short8 r1 = *(const short8*)&Xb[srow * LSTR + c16 + 8];
        size_t o = ((size_t)bh * HD + srow) * SSZ + sbase + c16;
        *(short8*)&vt[o] = r0;
        *(short8*)&vt[o + 8] = r1;
    }
}

// ---------------- Kernel 2: flash attention, 32x32 MFMA + in-reg softmax ----
// Compute core identical to round 4 (swapped QK^T, cvt_pk+permlane32_swap
// in-register P rebuild, lacc via ones-MFMA). Staging reverted to the
// round-0-PROVEN skeleton: register prefetch -> ds_write -> two
// __syncthreads per tile (compiler-managed fences; no inline-asm sync).
// LDS is FRAGMENT-MAJOR: Kfr[(row>>5)*8 + chunk][row&31][8] so every
// ds_read_b128 in the loop is one loop-invariant base + compile-time
// offset, lanes cover a dense lane-ordered 1KB region: conflict-free
// reads and writes, no XOR swizzle anywhere.
__global__ __launch_bounds__(512, 4) void attn_kernel(
    const short* __restrict__ qp, const short* __restrict__ kp,
    const short* __restrict__ vt, short* __restrict__ ctx)
{
    __shared__ __align__(16) short Kfr[16 * 32 * 8];   // 8 KB
    __shared__ __align__(16) short Vfr[16 * 32 * 8];   // 8 KB

    int tid = threadIdx.x;
    int wave = tid >> 6, lane = tid & 63;
    int hi = lane >> 5, l31 = lane & 31;
    int bh = blockIdx.x;
    int b = bh >> 4, h = bh & 15;
    int qrow0 = blockIdx.y * 256 + wave * 32;

    const short* Qb = qp + (size_t)bh * SSZ * HD;
    const short* Kb = kp + (size_t)bh * SSZ * HD;
    const short* Vb = vt + (size_t)bh * HD * SSZ;

    // staging: thread covers global row = wave*8 + (lane>>3), 16B chunk pc
    int lrow = lane >> 3, pc = lane & 7;
    int grow = wave * 8 + lrow;
    const short* ksrc = Kb + (size_t)grow * HD + pc * 8;
    const short* vsrc = Vb + (size_t)grow * SSZ + pc * 8;
    int fidx = (((grow >> 5) * 8 + pc) * 32 + (grow & 31)) * 8;
    short* kdst = &Kfr[fidx];
    short* vdst = &Vfr[fidx];

    // Q fragments (B-operand): B[col=q=l31][k=d = s*16 + hi*8 + j]
    short8 qf[4];
#pragma unroll
    for (int s = 0; s < 4; ++s)
        qf[s] = *(const short8*)&Qb[(size_t)(qrow0 + l31) * HD + s * 16 + hi * 8];

    // loop-invariant LDS read bases; all offsets are compile-time constants
    const short* krd = &Kfr[(hi * 32 + l31) * 8];
    const short* vrd = &Vfr[(hi * 32 + l31) * 8];

    const short one = (short)0x3F80;
    short8 ones = {one, one, one, one, one, one, one, one};

    float16v oacc0 = (float16v)(0.f);   // d 0..31
    float16v oacc1 = (float16v)(0.f);   // d 32..63
    float16v lacc  = (float16v)(0.f);   // row-sums, same C layout as oacc

    // prologue: stage tile 0
    {
        short8 kr = *(const short8*)ksrc;
        short8 vr = *(const short8*)vsrc;
        *(short8*)kdst = kr;
        *(short8*)vdst = vr;
    }
    __syncthreads();

    for (int kt = 0; kt < SSZ / 64; ++kt) {
        short8 krn, vrn;
        if (kt < SSZ / 64 - 1) {
            krn = *(const short8*)(ksrc + (size_t)(kt + 1) * (64 * HD));
            vrn = *(const short8*)(vsrc + (size_t)(kt + 1) * 64);
        }
#pragma unroll
        for (int t = 0; t < 2; ++t) {
            // QK^T swapped: sacc = K_tile-frag x Q-frag; D[row=kpos][col=q]
            float16v sacc = (float16v)(0.f);
#pragma unroll
            for (int s = 0; s < 4; ++s) {
                short8 kf = *(const short8*)(krd + (t * 8 + 2 * s) * 256);
                sacc = mfma32(kf, qf[s], sacc);
            }
            // lane holds P[q=l31][k_local=(r&3)+8*(r>>2)+4*hi] (t*32 offset)
#pragma unroll
            for (int sr = 0; sr < 2; ++sr) {
                unsigned x0 = cvtpk(fexp2(sacc[sr * 8 + 0]), fexp2(sacc[sr * 8 + 1]));
                unsigned x1 = cvtpk(fexp2(sacc[sr * 8 + 2]), fexp2(sacc[sr * 8 + 3]));
                unsigned y0 = cvtpk(fexp2(sacc[sr * 8 + 4]), fexp2(sacc[sr * 8 + 5]));
                unsigned y1 = cvtpk(fexp2(sacc[sr * 8 + 6]), fexp2(sacc[sr * 8 + 7]));
                // swap hi-half of x with lo-half of y: yields A-frag words
                asm("v_permlane32_swap_b32 %0, %1" : "+v"(x0), "+v"(y0));
                asm("v_permlane32_swap_b32 %0, %1" : "+v"(x1), "+v"(y1));
                uint4v wv; wv[0] = x0; wv[1] = x1; wv[2] = y0; wv[3] = y1;
                short8 pa = __builtin_bit_cast(short8, wv);
                int sa = t * 2 + sr;   // 16-k step within KVBLK
                short8 vf0 = *(const short8*)(vrd + (2 * sa) * 256);
                short8 vf1 = *(const short8*)(vrd + (8 + 2 * sa) * 256);
                oacc0 = mfma32(pa, vf0, oacc0);
                oacc1 = mfma32(pa, vf1, oacc1);
                lacc  = mfma32(pa, ones, lacc);   // row-sum, same C layout
            }
        }
        __syncthreads();
        if (kt < SSZ / 64 - 1) {
            *(short8*)kdst = krn;
            *(short8*)vdst = vrn;
        }
        __syncthreads();
    }

    // epilogue: lacc rows align with oacc rows; no cross-lane work needed
#pragma unroll
    for (int g = 0; g < 4; ++g)
#pragma unroll
        for (int e = 0; e < 4; ++e) {
            int r = g * 4 + e;
            float rl = 1.0f / lacc[r];
            int q = qrow0 + g * 8 + 4 * hi + e;
            size_t o = (size_t)(b * SSZ + q) * EMBED + h * HD + l31;
            ctx[o]      = f2bf(oacc0[r] * rl);
            ctx[o + 32] = f2bf(oacc1[r] * rl);
        }
}

// ---------------- Kernel 3: output projection (m97-style, glds staging) ----
// out = ctx @ Wp^T + bp. M=8192 N=1024 K=1024, tile 128x128, BK=64.
// grid (64, 8), block 256 (2x2 waves, each 64x64 via 4x4 acc).
__global__ __launch_bounds__(256) void proj_kernel(
    const short* __restrict__ ctx, const short* __restrict__ Wpb,
    const float* __restrict__ bp, float* __restrict__ out)
{
    __shared__ __align__(16) short Als[128 * 64];  // [m][k] 16 KB
    __shared__ __align__(16) short Bls[128 * 64];  // [n][k] 16 KB

    int tid = threadIdx.x;
    int wave = tid >> 6, lane = tid & 63, quad = lane >> 4, l16 = lane & 15;
    int wm = wave >> 1, wn = wave & 1;
    int row0 = blockIdx.x * 128;
    int col0 = blockIdx.y * 128;

    // staging: each wave covers 32 rows (4 issues x 8 rows); lane -> (row, col)
    int lrow = lane >> 3;            // 0..7
    int lcol = (lane & 7) * 8;       // 0..56 shorts
    const short* ag = ctx + (size_t)(row0 + wave * 32 + lrow) * EMBED + lcol;
    const short* bg = Wpb + (size_t)(col0 + wave * 32 + lrow) * EMBED + lcol;

    float4v acc[4][4];
#pragma unroll
    for (int mt = 0; mt < 4; ++mt)
#pragma unroll
        for (int nt = 0; nt < 4; ++nt) acc[mt][nt] = (float4v)(0.f);

    for (int kc = 0; kc < EMBED / 64; ++kc) {
#pragma unroll
        for (int i = 0; i < 4; ++i) {
            glds16(ag + (size_t)(i * 8) * EMBED + kc * 64,
                   &Als[(wave * 32 + i * 8) * 64]);
            glds16(bg + (size_t)(i * 8) * EMBED + kc * 64,
                   &Bls[(wave * 32 + i * 8) * 64]);
        }
        __syncthreads();   // drains vmcnt (DMA) + orders LDS
#pragma unroll
        for (int ks = 0; ks < 2; ++ks) {
            short8 af[4], bf[4];
#pragma unroll
            for (int mt = 0; mt < 4; ++mt)
                af[mt] = *(const short8*)&Als[(wm * 64 + mt * 16 + l16) * 64 + ks * 32 + quad * 8];
#pragma unroll
            for (int nt = 0; nt < 4; ++nt)
                bf[nt] = *(const short8*)&Bls[(wn * 64 + nt * 16 + l16) * 64 + ks * 32 + quad * 8];
#pragma unroll
            for (int mt = 0; mt < 4; ++mt)
#pragma unroll
                for (int nt = 0; nt < 4; ++nt)
                    acc[mt][nt] = mfma16(af[mt], bf[nt], acc[mt][nt]);
        }
        __syncthreads();   // all reads done before next staging overwrites
    }
#pragma unroll
    for (int nt = 0; nt < 4; ++nt) {
        float bias = bp[col0 + wn * 64 + nt * 16 + l16];
#pragma unroll
        for (int mt = 0; mt < 4; ++mt)
#pragma unroll
            for (int r = 0; r < 4; ++r) {
                int row = row0 + wm * 64 + mt * 16 + quad * 4 + r;
                out[(size_t)row * EMBED + col0 + wn * 64 + nt * 16 + l16] = acc[mt][nt][r] + bias;
            }
    }
}

extern "C" void kernel_launch(void* const* d_in, const int* in_sizes, int n_in,
                              void* d_out, int out_size, void* d_ws, size_t ws_size,
                              hipStream_t stream) {
    const float* q_in = (const float*)d_in[0];
    const float* k_in = (const float*)d_in[1];
    const float* v_in = (const float*)d_in[2];
    const float* Wq   = (const float*)d_in[3];
    const float* bq   = (const float*)d_in[4];
    const float* Wk   = (const float*)d_in[5];
    const float* bk   = (const float*)d_in[6];
    const float* Wv   = (const float*)d_in[7];
    const float* bv   = (const float*)d_in[8];
    const float* Wp   = (const float*)d_in[9];
    const float* bp   = (const float*)d_in[10];

    const size_t TENS = (size_t)BSZ * SSZ * EMBED;
    short* ws  = (short*)d_ws;
    short* qp  = ws;
    short* kp  = qp + TENS;
    short* vtp = kp + TENS;
    short* ctx = vtp + TENS;
    short* wpb = ctx + TENS;

    wp_cvt_kernel<<<dim3(EMBED * EMBED / 1024), 256, 0, stream>>>(Wp, wpb);
    qkv_kernel<<<dim3(BSZ * SSZ / 64, NH, 3), 256, 0, stream>>>(
        q_in, k_in, v_in, Wq, bq, Wk, bk, Wv, bv, qp, kp, vtp);
    attn_kernel<<<dim3(BSZ * NH, SSZ / 256), 512, 0, stream>>>(qp, kp, vtp, ctx);
    proj_kernel<<<dim3(BSZ * SSZ / 128, EMBED / 128), 256, 0, stream>>>(
        ctx, wpb, bp, (float*)d_out);
}